// Round 5
// baseline (432.336 us; speedup 1.0000x reference)
//
#include <hip/hip_runtime.h>
#include <hip/hip_bf16.h>
#include <math.h>

#define NTOK   65536
#define L_SEQ  16384

typedef __bf16 bf16_t;
typedef bf16_t bf16x8 __attribute__((ext_vector_type(8)));
typedef bf16_t bf16x4 __attribute__((ext_vector_type(4)));
typedef float  f32x4  __attribute__((ext_vector_type(4)));

__device__ inline float phi_f(float x) { return x > 0.f ? x + 1.f : __expf(x); }

__device__ inline float quad_sum(float v) {
    v += __shfl_xor(v, 1);
    v += __shfl_xor(v, 2);
    v += __shfl_xor(v, 4);
    v += __shfl_xor(v, 8);
    return v;
}

__device__ inline float ld_any(const void* p, size_t i, int f32) {
    return f32 ? ((const float*)p)[i] : (float)((const bf16_t*)p)[i];
}

// async 16B global->LDS (direct-to-shared DMA; HW dest = wave-uniform base +
// lane*16 — callers below always pass lds ptrs of exactly that shape)
__device__ inline void async_copy16(const bf16_t* g, bf16_t* l) {
    __builtin_amdgcn_global_load_lds(
        (const __attribute__((address_space(1))) unsigned int*)g,
        (__attribute__((address_space(3))) unsigned int*)l, 16, 0, 0);
}

// Stage nslot 16-B units (8 bf16 each; nslot = elements/8) of a
// [rows][rowstride] bf16 slice into LDS with an XOR swizzle of the
// (1<<ulog2) units per row: phys j = u ^ (n & (U-1)).
__device__ inline void stage_swz(const bf16_t* __restrict__ g, bf16_t* lds,
                                 int tid, int nslot, int ulog2, int rowstride) {
    const int umask = (1 << ulog2) - 1;
    for (int s = tid; s < nslot; s += 256) {
        int n = s >> ulog2, j = s & umask;
        int u = j ^ (n & umask);
        async_copy16(g + (size_t)n * rowstride + u * 8, lds + (size_t)s * 8);
    }
}

__device__ inline bf16x8 rd_swz(const bf16_t* lds, int n, int u, int ulog2) {
    int j = u ^ (n & ((1 << ulog2) - 1));
    return *(const bf16x8*)&lds[(((size_t)n << ulog2) + j) * 8];
}

// ---- W2 chunk [256 n][32 k] packed as [128 rows][64 cols] so LDS rows span
// 128B = all 32 banks (the [256][32] layout had 64B rows -> 4-way read
// conflicts, 8.9M SQ_LDS_BANK_CONFLICT in round 4). Row r = n&127, slot
// u = (n>>7)*4 + k/8, phys = u ^ (r&7).
__device__ inline void stage_w2ff(const bf16_t* __restrict__ W2_t, int ch,
                                  bf16_t* lds, int tid) {
    for (int S = tid; S < 1024; S += 256) {
        int r = S >> 3, phys = S & 7;
        int u = phys ^ (r & 7);
        int n = ((u >> 2) << 7) + r;
        int ks = u & 3;
        async_copy16(W2_t + (size_t)n * 1024 + ch * 32 + ks * 8, lds + (size_t)S * 8);
    }
}

__device__ inline bf16x8 rd_w2ff(const bf16_t* lds, int n, int quad) {
    int r = n & 127;
    int u = ((n >> 7) << 2) + quad;
    int phys = u ^ (r & 7);
    return *(const bf16x8*)&lds[(size_t)(r * 8 + phys) * 8];
}

// A-frags for one wave: row m, k = kk*32 + quad*8, kk=0..7 (K=256)
__device__ inline void ld_afrags(const bf16_t* __restrict__ tile, int row, int q8,
                                 bf16x8 a[8]) {
#pragma unroll
    for (int kk = 0; kk < 8; ++kk)
        a[kk] = *(const bf16x8*)&tile[(size_t)row * 256 + kk * 32 + q8];
}

// ------------------------------------------------- K-1: dtype probe
__global__ __launch_bounds__(256) void k_detect(const void* __restrict__ xraw,
                                                int* __restrict__ flag) {
    __shared__ int bad;
    if (threadIdx.x == 0) bad = 0;
    __syncthreads();
    const bf16_t* xb = (const bf16_t*)xraw;
    int mybad = 0;
#pragma unroll
    for (int j = 0; j < 16; ++j) {
        float v = fabsf((float)xb[threadIdx.x + 256 * j]);
        if (!(v <= 1000.f)) mybad = 1;
    }
    if (mybad) atomicOr(&bad, 1);
    __syncthreads();
    if (threadIdx.x == 0) *flag = bad;
}

// ------------------------------------------------- K0a: x -> canonical bf16
__global__ __launch_bounds__(256) void k_convert(const void* __restrict__ xraw,
                                                 const int* __restrict__ flag,
                                                 bf16_t* __restrict__ xbf) {
    const int f = *flag;
    size_t i = ((size_t)blockIdx.x * 256 + threadIdx.x) * 4;
    if (f) {
        f32x4 v = *(const f32x4*)((const float*)xraw + i);
        bf16x4 o;
#pragma unroll
        for (int j = 0; j < 4; ++j) o[j] = (bf16_t)v[j];
        *(bf16x4*)&xbf[i] = o;
    } else {
        *(bf16x4*)&xbf[i] = *(const bf16x4*)((const bf16_t*)xraw + i);
    }
}

// ------------------------------------------------- K0b: weight transpose + bias pack
__global__ __launch_bounds__(256) void k_prep(
    const void* __restrict__ Wq, const void* __restrict__ Wk,
    const void* __restrict__ Wv, const void* __restrict__ Wo,
    const void* __restrict__ W1, const void* __restrict__ W2,
    const void* __restrict__ bq, const void* __restrict__ bk,
    const void* __restrict__ bv, const void* __restrict__ bo,
    const void* __restrict__ b1, const void* __restrict__ b2,
    const void* __restrict__ g1, const void* __restrict__ be1,
    const void* __restrict__ g2, const void* __restrict__ be2,
    const int* __restrict__ flag,
    bf16_t* __restrict__ Wqkv_t, bf16_t* __restrict__ Wo_t,
    bf16_t* __restrict__ W1_t, bf16_t* __restrict__ W2_t,
    bf16_t* __restrict__ pbuf, float* __restrict__ kvbuf) {
    const int f = *flag;
    int idx = blockIdx.x * 256 + threadIdx.x;
    if (idx < 196608) {                       // Wqkv_t [768][256]
        int n = idx >> 8, k = idx & 255;
        float v;
        if (n < 256)      v = ld_any(Wq, k * 256 + n, f);
        else if (n < 512) v = ld_any(Wk, k * 256 + (n - 256), f);
        else              v = ld_any(Wv, k * 256 + (n - 512), f);
        Wqkv_t[idx] = (bf16_t)v;
    } else if (idx < 262144) {                // Wo_t [256][256]
        int i = idx - 196608; int n = i >> 8, k = i & 255;
        Wo_t[i] = (bf16_t)ld_any(Wo, k * 256 + n, f);
    } else if (idx < 524288) {                // W1_t [1024][256]
        int i = idx - 262144; int n = i >> 8, k = i & 255;
        W1_t[i] = (bf16_t)ld_any(W1, k * 1024 + n, f);
    } else if (idx < 786432) {                // W2_t [256][1024]
        int i = idx - 524288; int n = i >> 10, k = i & 1023;
        W2_t[i] = (bf16_t)ld_any(W2, k * 256 + n, f);
    } else if (idx < 820224) {                // KV state zero-init
        kvbuf[idx - 786432] = 0.f;
    } else if (idx < 823552) {                // bias/param pack
        int i = idx - 820224;
        float v;
        if (i < 256)        v = ld_any(bq, i, f);
        else if (i < 512)   v = ld_any(bk, i - 256, f);
        else if (i < 768)   v = ld_any(bv, i - 512, f);
        else if (i < 1024)  v = ld_any(bo, i - 768, f);
        else if (i < 2048)  v = ld_any(b1, i - 1024, f);
        else if (i < 2304)  v = ld_any(b2, i - 2048, f);
        else if (i < 2560)  v = ld_any(g1, i - 2304, f);
        else if (i < 2816)  v = ld_any(be1, i - 2560, f);
        else if (i < 3072)  v = ld_any(g2, i - 2816, f);
        else                v = ld_any(be2, i - 3072, f);
        pbuf[i] = (bf16_t)v;
    }
}

// ------------------------------------------------- K1: QKV GEMM + phi
// grid (1024, 6): M=64, N=128 per block. A stationary in regs, B via
// global_load_lds. Tile 128x256 = 4096 slots (= elements/8). LDS 64KB.
__global__ __launch_bounds__(256, 4) void k_qkv(
    const bf16_t* __restrict__ x, const bf16_t* __restrict__ Wqkv_t,
    const bf16_t* __restrict__ pbuf,
    bf16_t* __restrict__ q_phi, bf16_t* __restrict__ k_phi,
    bf16_t* __restrict__ v_out) {
    const int mt = blockIdx.x, nt = blockIdx.y;
    const int tid = threadIdx.x, wave = tid >> 6, lane = tid & 63;
    const int l15 = lane & 15, quad = lane >> 4, q8 = quad * 8;
    __shared__ __align__(16) bf16_t bs[128 * 256];
    const int m0 = mt * 64;
    bf16x8 a[8];
    ld_afrags(x + (size_t)m0 * 256, wave * 16 + l15, q8, a);
    stage_swz(Wqkv_t + (size_t)nt * 128 * 256, bs, tid, 4096, 5, 256);
    __syncthreads();
    f32x4 acc[8] = {};
#pragma unroll
    for (int kk = 0; kk < 8; ++kk) {
#pragma unroll
        for (int s = 0; s < 8; ++s) {
            bf16x8 b = rd_swz(bs, s * 16 + l15, kk * 4 + quad, 5);
            acc[s] = __builtin_amdgcn_mfma_f32_16x16x32_bf16(a[kk], b, acc[s], 0, 0, 0);
        }
    }
#pragma unroll
    for (int s = 0; s < 8; ++s) {
        int ng = nt * 128 + s * 16 + l15;
        bf16_t* dst = ng < 256 ? q_phi : (ng < 512 ? k_phi : v_out);
        int nl = ng & 255;
        float bias = (float)pbuf[(ng < 256 ? 0 : (ng < 512 ? 256 : 512)) + nl];
#pragma unroll
        for (int r = 0; r < 4; ++r) {
            int m = m0 + wave * 16 + quad * 4 + r;
            float val = acc[s][r] + bias;
            if (ng < 512) val = phi_f(val);
            dst[(size_t)m * 256 + nl] = (bf16_t)val;
        }
    }
}

// ------------------------------------------------- K2: KV state reduction
// Writes kv TRANSPOSED: kvbuf slot [e*32+d] = sum_l k_phi[l][d]*v[l][e]
// (e-major so the apply-side MFMA B-fragment is one contiguous bf16x8).
__global__ __launch_bounds__(256) void k_kvsum(
    const bf16_t* __restrict__ k_phi, const bf16_t* __restrict__ v_in,
    float* __restrict__ kvbuf) {
    const int bid = blockIdx.x;
    const int bh = bid >> 6, ck = bid & 63;
    const int b = bh >> 3, h = bh & 7;
    const int tid = threadIdx.x;
    __shared__ float ks[32][33], vs[32][33];
    const size_t base = ((size_t)b * L_SEQ + ck * 256) * 256 + h * 32;
    const int row = tid >> 3, c4 = (tid & 7) * 4;
    const int d = row, e4 = c4;
    float acc[4] = {}, ksacc = 0.f;
    for (int it = 0; it < 8; ++it) {
        bf16x4 kk4 = *(const bf16x4*)&k_phi[base + (size_t)(it * 32 + row) * 256 + c4];
        bf16x4 vv4 = *(const bf16x4*)&v_in[base + (size_t)(it * 32 + row) * 256 + c4];
#pragma unroll
        for (int j = 0; j < 4; ++j) { ks[row][c4 + j] = (float)kk4[j]; vs[row][c4 + j] = (float)vv4[j]; }
        __syncthreads();
#pragma unroll
        for (int ii = 0; ii < 32; ++ii) {
            float kd = ks[ii][d];
            ksacc += kd;
#pragma unroll
            for (int j = 0; j < 4; ++j) acc[j] += kd * vs[ii][e4 + j];
        }
        __syncthreads();
    }
    float* kvdst = kvbuf + (size_t)bh * 1056;
#pragma unroll
    for (int j = 0; j < 4; ++j) atomicAdd(&kvdst[(e4 + j) * 32 + d], acc[j]);
    if ((tid & 7) == 0) atomicAdd(&kvdst[1024 + d], ksacc);
}

// ------------------------------------------------- K2b: kv f32 -> bf16 pack
// kvbf[bh*1024 + e*32 + d] = (bf16) kvbuf[bh*1056 + e*32 + d]
__global__ __launch_bounds__(256) void k_kvprep(const float* __restrict__ kvbuf,
                                                bf16_t* __restrict__ kvbf) {
    int idx = blockIdx.x * 256 + threadIdx.x;       // 8192 total
    int bh = idx >> 8, r4 = (idx & 255) * 4;
    f32x4 v = *(const f32x4*)&kvbuf[(size_t)bh * 1056 + r4];
    bf16x4 o;
#pragma unroll
    for (int j = 0; j < 4; ++j) o[j] = (bf16_t)v[j];
    *(bf16x4*)&kvbf[(size_t)bh * 1024 + r4] = o;
}

// ------------------------------------------------- K3+K4 fused: attention
// apply (q_phi @ kv * z) + @Wo + x residual + LN1.
// Wo chunks 32x256 (16KB), 8 chunks, 1 barrier per chunk ping-pong.
// sm0 16KB + sm1 33KB (hs union) = 49.4KB -> >=2 blocks/CU.
__global__ __launch_bounds__(256, 3) void k_attn_wo_ln1(
    const bf16_t* __restrict__ q_phi, const bf16_t* __restrict__ kvbf,
    const float* __restrict__ kvbuf, const bf16_t* __restrict__ Wo_t,
    const bf16_t* __restrict__ pbuf, const void* __restrict__ xraw,
    const int* __restrict__ flag, bf16_t* __restrict__ x1) {
    const int f = *flag;
    const int mt = blockIdx.x;
    const int tid = threadIdx.x, wave = tid >> 6, lane = tid & 63;
    const int l15 = lane & 15, quad = lane >> 4, q8 = quad * 8;
    __shared__ __align__(16) bf16_t sm0[8192];         // Wo chunk (nc even), 16KB
    __shared__ __align__(16) bf16_t sm1[16896];        // hs, then Wo chunk (nc odd)
    const int m0 = mt * 64;
    const int b = m0 >> 14;                            // batch index
    bf16x8 a[8];
    ld_afrags(q_phi + (size_t)m0 * 256, wave * 16 + l15, q8, a);
    stage_swz(Wo_t, sm0, tid, 1024, 5, 256);           // async chunk0 (32 rows)
    // ---------------- attention phase (wave-local, no barrier) ----------------
    bf16_t* hs = sm1 + wave * (16 * 264);              // [16 rows][264 cols]
    const bf16_t* kvb = kvbf + (size_t)b * 8192;       // 8 heads * 1024 bf16
    const float*  ksb = kvbuf + (size_t)b * 8448;      // 8 heads * 1056 f32
#pragma unroll
    for (int h = 0; h < 8; ++h) {
        // denominator: q[m=l15][h*32 + quad*8+j] . ksum
        f32x4 ks0 = *(const f32x4*)&ksb[h * 1056 + 1024 + q8];
        f32x4 ks1 = *(const f32x4*)&ksb[h * 1056 + 1024 + q8 + 4];
        float den = 0.f;
#pragma unroll
        for (int j = 0; j < 4; ++j) den += (float)a[h][j] * ks0[j];
#pragma unroll
        for (int j = 0; j < 4; ++j) den += (float)a[h][4 + j] * ks1[j];
        den += __shfl_xor(den, 16);                    // reduce across quads
        den += __shfl_xor(den, 32);
        float z = 1.f / (den + 1e-6f);                 // z for row = l15
        float zr[4];
#pragma unroll
        for (int r = 0; r < 4; ++r) zr[r] = __shfl(z, quad * 4 + r, 16);
        // numerator: B[k=d][n=e] = kv[d][e], stored e-major -> contiguous frag
        bf16x8 b0 = *(const bf16x8*)&kvb[h * 1024 + l15 * 32 + q8];
        bf16x8 b1 = *(const bf16x8*)&kvb[h * 1024 + (16 + l15) * 32 + q8];
        f32x4 at0 = {}, at1 = {};
        at0 = __builtin_amdgcn_mfma_f32_16x16x32_bf16(a[h], b0, at0, 0, 0, 0);
        at1 = __builtin_amdgcn_mfma_f32_16x16x32_bf16(a[h], b1, at1, 0, 0, 0);
#pragma unroll
        for (int r = 0; r < 4; ++r) {                  // C-layout: row=quad*4+r, col=l15
            hs[(quad * 4 + r) * 264 + h * 32 + l15]      = (bf16_t)(at0[r] * zr[r]);
            hs[(quad * 4 + r) * 264 + h * 32 + 16 + l15] = (bf16_t)(at1[r] * zr[r]);
        }
    }
    // wave-local C->A layout round-trip (in-order DS pipe within wave)
    bf16x8 a2[8];
#pragma unroll
    for (int kk = 0; kk < 8; ++kk)
        a2[kk] = *(const bf16x8*)&hs[l15 * 264 + kk * 32 + q8];
    __syncthreads();       // sm0 chunk0 staged; all waves done with hs (sm1)
    // ---------------- Wo GEMM, 8 chunks of 32 cols, ping-pong sm0/sm1 --------
    f32x4 acc[16] = {};
    for (int nc = 0; nc < 8; ++nc) {
        if (nc < 7) stage_swz(Wo_t + (size_t)(nc + 1) * 32 * 256,
                              (nc & 1) ? sm0 : sm1, tid, 1024, 5, 256);
        const bf16_t* buf = (nc & 1) ? sm1 : sm0;
#pragma unroll
        for (int kk = 0; kk < 8; ++kk) {
#pragma unroll
            for (int s = 0; s < 2; ++s) {
                bf16x8 bb = rd_swz(buf, s * 16 + l15, kk * 4 + quad, 5);
                acc[nc * 2 + s] = __builtin_amdgcn_mfma_f32_16x16x32_bf16(a2[kk], bb, acc[nc * 2 + s], 0, 0, 0);
            }
        }
        __syncthreads();   // publishes next chunk, protects current from overwrite
    }
    // ---------------- epilogue: bias + x residual + LN1 ----------------
    float s1[4] = {}, s2[4] = {};
#pragma unroll
    for (int s = 0; s < 16; ++s) {
        int n = s * 16 + l15;
        float bias = (float)pbuf[768 + n];
#pragma unroll
        for (int r = 0; r < 4; ++r) {
            int m = m0 + wave * 16 + quad * 4 + r;
            float val = acc[s][r] + bias + ld_any(xraw, (size_t)m * 256 + n, f);
            acc[s][r] = val;
            s1[r] += val; s2[r] += val * val;
        }
    }
#pragma unroll
    for (int r = 0; r < 4; ++r) {
        float ts = quad_sum(s1[r]), ts2 = quad_sum(s2[r]);
        float mu = ts * (1.f / 256.f);
        float rs = rsqrtf(ts2 * (1.f / 256.f) - mu * mu + 1e-5f);
        s1[r] = mu; s2[r] = rs;
    }
#pragma unroll
    for (int s = 0; s < 16; ++s) {
        int n = s * 16 + l15;
        float gn = (float)pbuf[2304 + n], bn = (float)pbuf[2560 + n];
#pragma unroll
        for (int r = 0; r < 4; ++r) {
            int m = m0 + wave * 16 + quad * 4 + r;
            x1[(size_t)m * 256 + n] = (bf16_t)((acc[s][r] - s1[r]) * s2[r] * gn + bn);
        }
    }
}

// ------------------------------------------------- K5: fused FFN + LN2
// Round 5: (a) w2s repacked [128][64] -> conflict-free reads (was 8.9M
// conflict-cycles at the [256][32] 64B-row layout); (b) single barrier per
// chunk via full double-buffer: stage ch+1 into idle buffers at top of
// iter ch, compute both GEMM steps from current buffers, one barrier.
// LDS: w1s 2x16KB + w2s 2x8KB + hs 5KB = 53KB -> 3 blocks/CU.
__global__ __launch_bounds__(256, 3) void k_ff_ln2(
    const bf16_t* __restrict__ x1, const bf16_t* __restrict__ W1_t,
    const bf16_t* __restrict__ W2_t, const bf16_t* __restrict__ pbuf,
    const int* __restrict__ flag, void* __restrict__ out) {
    const int f32o = *flag;
    const int mt = blockIdx.x;
    const int tid = threadIdx.x, wave = tid >> 6, lane = tid & 63;
    const int l15 = lane & 15, quad = lane >> 4, q8 = quad * 8;
    __shared__ __align__(16) bf16_t w1s[2][8192];     // 32 ff-rows x 256 K each
    __shared__ __align__(16) bf16_t w2s[2][8192];     // [128][64] packed chunk
    __shared__ __align__(16) bf16_t hs[4][16][40];    // wave-private h round-trip
    const int m0 = mt * 64;
    bf16x8 a[8];
    ld_afrags(x1 + (size_t)m0 * 256, wave * 16 + l15, q8, a);
    stage_swz(W1_t, w1s[0], tid, 1024, 5, 256);
    stage_w2ff(W2_t, 0, w2s[0], tid);
    __syncthreads();
    f32x4 acc[16] = {};
    for (int ch = 0; ch < 32; ++ch) {
        const int cur = ch & 1;
        // prefetch next chunk into the buffers consumed two iterations ago
        if (ch < 31) {
            stage_swz(W1_t + (size_t)(ch + 1) * 32 * 256, w1s[cur ^ 1], tid, 1024, 5, 256);
            stage_w2ff(W2_t, ch + 1, w2s[cur ^ 1], tid);
        }
        // step a: h = relu(x1 @ W1_chunk + b1), 32 ff-cols
        f32x4 hacc[2] = {};
#pragma unroll
        for (int kk = 0; kk < 8; ++kk) {
#pragma unroll
            for (int s = 0; s < 2; ++s) {
                bf16x8 b = rd_swz(w1s[cur], s * 16 + l15, kk * 4 + quad, 5);
                hacc[s] = __builtin_amdgcn_mfma_f32_16x16x32_bf16(a[kk], b, hacc[s], 0, 0, 0);
            }
        }
#pragma unroll
        for (int s = 0; s < 2; ++s) {
            float bias = (float)pbuf[1024 + ch * 32 + s * 16 + l15];
#pragma unroll
            for (int r = 0; r < 4; ++r) {
                float val = hacc[s][r] + bias;
                hs[wave][quad * 4 + r][s * 16 + l15] = (bf16_t)(val > 0.f ? val : 0.f);
            }
        }
        // wave-local C->A layout round-trip (in-order DS pipe within wave)
        bf16x8 a2 = *(const bf16x8*)&hs[wave][l15][q8];
        // step b: out += h_chunk @ W2_chunk
#pragma unroll
        for (int s = 0; s < 16; ++s) {
            bf16x8 b0 = rd_w2ff(w2s[cur], s * 16 + l15, quad);
            acc[s] = __builtin_amdgcn_mfma_f32_16x16x32_bf16(a2, b0, acc[s], 0, 0, 0);
        }
        __syncthreads();   // next-chunk stages complete; cur buffers reusable
    }
    // epilogue: + b2 + x1 residual, LN2, dual-dtype store
    float s1[4] = {}, s2[4] = {};
#pragma unroll
    for (int s = 0; s < 16; ++s) {
        int n = s * 16 + l15;
        float bias = (float)pbuf[2048 + n];
#pragma unroll
        for (int r = 0; r < 4; ++r) {
            int m = m0 + wave * 16 + quad * 4 + r;
            float val = acc[s][r] + bias + (float)x1[(size_t)m * 256 + n];
            acc[s][r] = val;
            s1[r] += val; s2[r] += val * val;
        }
    }
#pragma unroll
    for (int r = 0; r < 4; ++r) {
        float ts = quad_sum(s1[r]), ts2 = quad_sum(s2[r]);
        float mu = ts * (1.f / 256.f);
        float rs = rsqrtf(ts2 * (1.f / 256.f) - mu * mu + 1e-5f);
        s1[r] = mu; s2[r] = rs;
    }
#pragma unroll
    for (int s = 0; s < 16; ++s) {
        int n = s * 16 + l15;
        float gn = (float)pbuf[2816 + n], bn = (float)pbuf[3072 + n];
#pragma unroll
        for (int r = 0; r < 4; ++r) {
            int m = m0 + wave * 16 + quad * 4 + r;
            float val = (acc[s][r] - s1[r]) * s2[r] * gn + bn;
            if (f32o) ((float*)out)[(size_t)m * 256 + n] = val;
            else      ((bf16_t*)out)[(size_t)m * 256 + n] = (bf16_t)val;
        }
    }
}

// ------------------------------------------------- launch
extern "C" void kernel_launch(void* const* d_in, const int* in_sizes, int n_in,
                              void* d_out, int out_size, void* d_ws, size_t ws_size,
                              hipStream_t stream) {
    char* ws = (char*)d_ws;
    int*    flag   = (int*)ws;                              // 4 B (256 reserved)
    bf16_t* xbf    = (bf16_t*)(ws + 256);                   // 16.7M elems
    bf16_t* Wqkv_t = (bf16_t*)(ws + 33554688);              // 196608
    bf16_t* Wo_t   = (bf16_t*)(ws + 33947904);              // 65536
    bf16_t* W1_t   = (bf16_t*)(ws + 34078976);              // 262144
    bf16_t* W2_t   = (bf16_t*)(ws + 34603264);              // 262144
    bf16_t* pbuf   = (bf16_t*)(ws + 35127552);              // 3328
    float*  kvbuf  = (float*)(ws + 35134208);               // 33792 f32
    bf16_t* bufQ   = (bf16_t*)(ws + 35269376);              // 16.7M elems
    bf16_t* bufK   = bufQ + (size_t)NTOK * 256;
    bf16_t* bufV   = bufK + (size_t)NTOK * 256;
    bf16_t* kvbf   = bufV;    // V dead after k_kvsum; reuse 64KB for bf16 kv
    bf16_t* bufX1  = bufQ;    // Q read + overwritten row-local in k_attn_wo_ln1

    k_detect<<<1, 256, 0, stream>>>(d_in[0], flag);
    k_convert<<<16384, 256, 0, stream>>>(d_in[0], flag, xbf);
    k_prep<<<3217, 256, 0, stream>>>(d_in[1], d_in[3], d_in[5], d_in[7],
                                     d_in[9], d_in[11],
                                     d_in[2], d_in[4], d_in[6], d_in[8],
                                     d_in[10], d_in[12],
                                     d_in[13], d_in[14], d_in[15], d_in[16],
                                     flag, Wqkv_t, Wo_t, W1_t, W2_t, pbuf, kvbuf);
    k_qkv<<<dim3(1024, 6), 256, 0, stream>>>(xbf, Wqkv_t, pbuf, bufQ, bufK, bufV);
    k_kvsum<<<2048, 256, 0, stream>>>(bufK, bufV, kvbuf);
    k_kvprep<<<32, 256, 0, stream>>>(kvbuf, kvbf);
    k_attn_wo_ln1<<<1024, 256, 0, stream>>>(bufQ, kvbf, kvbuf, Wo_t, pbuf,
                                            d_in[0], flag, bufX1);
    k_ff_ln2<<<1024, 256, 0, stream>>>(bufX1, W1_t, W2_t, pbuf, flag, d_out);
}

// Round 6
// 409.026 us; speedup vs baseline: 1.0570x; 1.0570x over previous
//
#include <hip/hip_runtime.h>
#include <hip/hip_bf16.h>
#include <math.h>

#define NTOK   65536
#define L_SEQ  16384

typedef __bf16 bf16_t;
typedef bf16_t bf16x8 __attribute__((ext_vector_type(8)));
typedef bf16_t bf16x4 __attribute__((ext_vector_type(4)));
typedef float  f32x4  __attribute__((ext_vector_type(4)));

__device__ inline float phi_f(float x) { return x > 0.f ? x + 1.f : __expf(x); }

__device__ inline float quad_sum(float v) {
    v += __shfl_xor(v, 1);
    v += __shfl_xor(v, 2);
    v += __shfl_xor(v, 4);
    v += __shfl_xor(v, 8);
    return v;
}

__device__ inline float ld_any(const void* p, size_t i, int f32) {
    return f32 ? ((const float*)p)[i] : (float)((const bf16_t*)p)[i];
}

// async 16B global->LDS (direct-to-shared DMA; HW dest = wave-uniform base +
// lane*16 — callers below always pass lds ptrs of exactly that shape)
__device__ inline void async_copy16(const bf16_t* g, bf16_t* l) {
    __builtin_amdgcn_global_load_lds(
        (const __attribute__((address_space(1))) unsigned int*)g,
        (__attribute__((address_space(3))) unsigned int*)l, 16, 0, 0);
}

// Stage nslot 16-B units (8 bf16 each; nslot = elements/8) of a
// [rows][rowstride] bf16 slice into LDS with an XOR swizzle of the
// (1<<ulog2) units per row: phys j = u ^ (n & (U-1)).
__device__ inline void stage_swz(const bf16_t* __restrict__ g, bf16_t* lds,
                                 int tid, int nslot, int ulog2, int rowstride) {
    const int umask = (1 << ulog2) - 1;
    for (int s = tid; s < nslot; s += 256) {
        int n = s >> ulog2, j = s & umask;
        int u = j ^ (n & umask);
        async_copy16(g + (size_t)n * rowstride + u * 8, lds + (size_t)s * 8);
    }
}

__device__ inline bf16x8 rd_swz(const bf16_t* lds, int n, int u, int ulog2) {
    int j = u ^ (n & ((1 << ulog2) - 1));
    return *(const bf16x8*)&lds[(((size_t)n << ulog2) + j) * 8];
}

// ---- W2 chunk [256 n][32 k] packed as [128 rows][64 cols] so LDS rows span
// 128B = all 32 banks (the [256][32] layout had 64B rows -> 4-way read
// conflicts, 8.9M SQ_LDS_BANK_CONFLICT in round 4). Row r = n&127, slot
// u = (n>>7)*4 + k/8, phys = u ^ (r&7). Verified conflict-free in round 5
// (0.52M residual conflicts).
__device__ inline void stage_w2ff(const bf16_t* __restrict__ W2_t, int ch,
                                  bf16_t* lds, int tid) {
    for (int S = tid; S < 1024; S += 256) {
        int r = S >> 3, phys = S & 7;
        int u = phys ^ (r & 7);
        int n = ((u >> 2) << 7) + r;
        int ks = u & 3;
        async_copy16(W2_t + (size_t)n * 1024 + ch * 32 + ks * 8, lds + (size_t)S * 8);
    }
}

__device__ inline bf16x8 rd_w2ff(const bf16_t* lds, int n, int quad) {
    int r = n & 127;
    int u = ((n >> 7) << 2) + quad;
    int phys = u ^ (r & 7);
    return *(const bf16x8*)&lds[(size_t)(r * 8 + phys) * 8];
}

// A-frags for one wave: row m, k = kk*32 + quad*8, kk=0..7 (K=256)
__device__ inline void ld_afrags(const bf16_t* __restrict__ tile, int row, int q8,
                                 bf16x8 a[8]) {
#pragma unroll
    for (int kk = 0; kk < 8; ++kk)
        a[kk] = *(const bf16x8*)&tile[(size_t)row * 256 + kk * 32 + q8];
}

// ------------------------------------------------- K-1: dtype probe
__global__ __launch_bounds__(256) void k_detect(const void* __restrict__ xraw,
                                                int* __restrict__ flag) {
    __shared__ int bad;
    if (threadIdx.x == 0) bad = 0;
    __syncthreads();
    const bf16_t* xb = (const bf16_t*)xraw;
    int mybad = 0;
#pragma unroll
    for (int j = 0; j < 16; ++j) {
        float v = fabsf((float)xb[threadIdx.x + 256 * j]);
        if (!(v <= 1000.f)) mybad = 1;
    }
    if (mybad) atomicOr(&bad, 1);
    __syncthreads();
    if (threadIdx.x == 0) *flag = bad;
}

// ------------------------------------------------- K0a: x -> canonical bf16
__global__ __launch_bounds__(256) void k_convert(const void* __restrict__ xraw,
                                                 const int* __restrict__ flag,
                                                 bf16_t* __restrict__ xbf) {
    const int f = *flag;
    size_t i = ((size_t)blockIdx.x * 256 + threadIdx.x) * 4;
    if (f) {
        f32x4 v = *(const f32x4*)((const float*)xraw + i);
        bf16x4 o;
#pragma unroll
        for (int j = 0; j < 4; ++j) o[j] = (bf16_t)v[j];
        *(bf16x4*)&xbf[i] = o;
    } else {
        *(bf16x4*)&xbf[i] = *(const bf16x4*)((const bf16_t*)xraw + i);
    }
}

// ------------------------------------------------- K0b: weight transpose + bias pack
__global__ __launch_bounds__(256) void k_prep(
    const void* __restrict__ Wq, const void* __restrict__ Wk,
    const void* __restrict__ Wv, const void* __restrict__ Wo,
    const void* __restrict__ W1, const void* __restrict__ W2,
    const void* __restrict__ bq, const void* __restrict__ bk,
    const void* __restrict__ bv, const void* __restrict__ bo,
    const void* __restrict__ b1, const void* __restrict__ b2,
    const void* __restrict__ g1, const void* __restrict__ be1,
    const void* __restrict__ g2, const void* __restrict__ be2,
    const int* __restrict__ flag,
    bf16_t* __restrict__ Wqkv_t, bf16_t* __restrict__ Wo_t,
    bf16_t* __restrict__ W1_t, bf16_t* __restrict__ W2_t,
    bf16_t* __restrict__ pbuf, float* __restrict__ kvbuf) {
    const int f = *flag;
    int idx = blockIdx.x * 256 + threadIdx.x;
    if (idx < 196608) {                       // Wqkv_t [768][256]
        int n = idx >> 8, k = idx & 255;
        float v;
        if (n < 256)      v = ld_any(Wq, k * 256 + n, f);
        else if (n < 512) v = ld_any(Wk, k * 256 + (n - 256), f);
        else              v = ld_any(Wv, k * 256 + (n - 512), f);
        Wqkv_t[idx] = (bf16_t)v;
    } else if (idx < 262144) {                // Wo_t [256][256]
        int i = idx - 196608; int n = i >> 8, k = i & 255;
        Wo_t[i] = (bf16_t)ld_any(Wo, k * 256 + n, f);
    } else if (idx < 524288) {                // W1_t [1024][256]
        int i = idx - 262144; int n = i >> 8, k = i & 255;
        W1_t[i] = (bf16_t)ld_any(W1, k * 1024 + n, f);
    } else if (idx < 786432) {                // W2_t [256][1024]
        int i = idx - 524288; int n = i >> 10, k = i & 1023;
        W2_t[i] = (bf16_t)ld_any(W2, k * 256 + n, f);
    } else if (idx < 820224) {                // KV state zero-init
        kvbuf[idx - 786432] = 0.f;
    } else if (idx < 823552) {                // bias/param pack
        int i = idx - 820224;
        float v;
        if (i < 256)        v = ld_any(bq, i, f);
        else if (i < 512)   v = ld_any(bk, i - 256, f);
        else if (i < 768)   v = ld_any(bv, i - 512, f);
        else if (i < 1024)  v = ld_any(bo, i - 768, f);
        else if (i < 2048)  v = ld_any(b1, i - 1024, f);
        else if (i < 2304)  v = ld_any(b2, i - 2048, f);
        else if (i < 2560)  v = ld_any(g1, i - 2304, f);
        else if (i < 2816)  v = ld_any(be1, i - 2560, f);
        else if (i < 3072)  v = ld_any(g2, i - 2816, f);
        else                v = ld_any(be2, i - 3072, f);
        pbuf[i] = (bf16_t)v;
    }
}

// ------------------------------------------------- K1: QKV GEMM + phi
// grid (1024, 6): M=64, N=128 per block. A stationary in regs, B via
// global_load_lds. Tile 128x256 = 4096 slots (= elements/8). LDS 64KB.
__global__ __launch_bounds__(256, 4) void k_qkv(
    const bf16_t* __restrict__ x, const bf16_t* __restrict__ Wqkv_t,
    const bf16_t* __restrict__ pbuf,
    bf16_t* __restrict__ q_phi, bf16_t* __restrict__ k_phi,
    bf16_t* __restrict__ v_out) {
    const int mt = blockIdx.x, nt = blockIdx.y;
    const int tid = threadIdx.x, wave = tid >> 6, lane = tid & 63;
    const int l15 = lane & 15, quad = lane >> 4, q8 = quad * 8;
    __shared__ __align__(16) bf16_t bs[128 * 256];
    const int m0 = mt * 64;
    bf16x8 a[8];
    ld_afrags(x + (size_t)m0 * 256, wave * 16 + l15, q8, a);
    stage_swz(Wqkv_t + (size_t)nt * 128 * 256, bs, tid, 4096, 5, 256);
    __syncthreads();
    f32x4 acc[8] = {};
#pragma unroll
    for (int kk = 0; kk < 8; ++kk) {
#pragma unroll
        for (int s = 0; s < 8; ++s) {
            bf16x8 b = rd_swz(bs, s * 16 + l15, kk * 4 + quad, 5);
            acc[s] = __builtin_amdgcn_mfma_f32_16x16x32_bf16(a[kk], b, acc[s], 0, 0, 0);
        }
    }
#pragma unroll
    for (int s = 0; s < 8; ++s) {
        int ng = nt * 128 + s * 16 + l15;
        bf16_t* dst = ng < 256 ? q_phi : (ng < 512 ? k_phi : v_out);
        int nl = ng & 255;
        float bias = (float)pbuf[(ng < 256 ? 0 : (ng < 512 ? 256 : 512)) + nl];
#pragma unroll
        for (int r = 0; r < 4; ++r) {
            int m = m0 + wave * 16 + quad * 4 + r;
            float val = acc[s][r] + bias;
            if (ng < 512) val = phi_f(val);
            dst[(size_t)m * 256 + nl] = (bf16_t)val;
        }
    }
}

// ------------------------------------------------- K2: KV state reduction
// Writes kv TRANSPOSED: kvbuf slot [e*32+d] = sum_l k_phi[l][d]*v[l][e]
// (e-major so the apply-side MFMA B-fragment is one contiguous bf16x8).
__global__ __launch_bounds__(256) void k_kvsum(
    const bf16_t* __restrict__ k_phi, const bf16_t* __restrict__ v_in,
    float* __restrict__ kvbuf) {
    const int bid = blockIdx.x;
    const int bh = bid >> 6, ck = bid & 63;
    const int b = bh >> 3, h = bh & 7;
    const int tid = threadIdx.x;
    __shared__ float ks[32][33], vs[32][33];
    const size_t base = ((size_t)b * L_SEQ + ck * 256) * 256 + h * 32;
    const int row = tid >> 3, c4 = (tid & 7) * 4;
    const int d = row, e4 = c4;
    float acc[4] = {}, ksacc = 0.f;
    for (int it = 0; it < 8; ++it) {
        bf16x4 kk4 = *(const bf16x4*)&k_phi[base + (size_t)(it * 32 + row) * 256 + c4];
        bf16x4 vv4 = *(const bf16x4*)&v_in[base + (size_t)(it * 32 + row) * 256 + c4];
#pragma unroll
        for (int j = 0; j < 4; ++j) { ks[row][c4 + j] = (float)kk4[j]; vs[row][c4 + j] = (float)vv4[j]; }
        __syncthreads();
#pragma unroll
        for (int ii = 0; ii < 32; ++ii) {
            float kd = ks[ii][d];
            ksacc += kd;
#pragma unroll
            for (int j = 0; j < 4; ++j) acc[j] += kd * vs[ii][e4 + j];
        }
        __syncthreads();
    }
    float* kvdst = kvbuf + (size_t)bh * 1056;
#pragma unroll
    for (int j = 0; j < 4; ++j) atomicAdd(&kvdst[(e4 + j) * 32 + d], acc[j]);
    if ((tid & 7) == 0) atomicAdd(&kvdst[1024 + d], ksacc);
}

// ------------------------------------------------- K2b: kv f32 -> bf16 pack
// kvbf[bh*1024 + e*32 + d] = (bf16) kvbuf[bh*1056 + e*32 + d]
__global__ __launch_bounds__(256) void k_kvprep(const float* __restrict__ kvbuf,
                                                bf16_t* __restrict__ kvbf) {
    int idx = blockIdx.x * 256 + threadIdx.x;       // 8192 total
    int bh = idx >> 8, r4 = (idx & 255) * 4;
    f32x4 v = *(const f32x4*)&kvbuf[(size_t)bh * 1056 + r4];
    bf16x4 o;
#pragma unroll
    for (int j = 0; j < 4; ++j) o[j] = (bf16_t)v[j];
    *(bf16x4*)&kvbf[(size_t)bh * 1024 + r4] = o;
}

// ------------------------------------------------- K3+K4 fused: attention
// apply (q_phi @ kv * z) + @Wo + x residual + LN1.
// Wo chunks 32x256 (16KB), 8 chunks, 1 barrier per chunk ping-pong.
// sm0 16KB + sm1 33KB (hs union) = 49.4KB -> >=2 blocks/CU.
__global__ __launch_bounds__(256, 3) void k_attn_wo_ln1(
    const bf16_t* __restrict__ q_phi, const bf16_t* __restrict__ kvbf,
    const float* __restrict__ kvbuf, const bf16_t* __restrict__ Wo_t,
    const bf16_t* __restrict__ pbuf, const void* __restrict__ xraw,
    const int* __restrict__ flag, bf16_t* __restrict__ x1) {
    const int f = *flag;
    const int mt = blockIdx.x;
    const int tid = threadIdx.x, wave = tid >> 6, lane = tid & 63;
    const int l15 = lane & 15, quad = lane >> 4, q8 = quad * 8;
    __shared__ __align__(16) bf16_t sm0[8192];         // Wo chunk (nc even), 16KB
    __shared__ __align__(16) bf16_t sm1[16896];        // hs, then Wo chunk (nc odd)
    const int m0 = mt * 64;
    const int b = m0 >> 14;                            // batch index
    bf16x8 a[8];
    ld_afrags(q_phi + (size_t)m0 * 256, wave * 16 + l15, q8, a);
    stage_swz(Wo_t, sm0, tid, 1024, 5, 256);           // async chunk0 (32 rows)
    // ---------------- attention phase (wave-local, no barrier) ----------------
    bf16_t* hs = sm1 + wave * (16 * 264);              // [16 rows][264 cols]
    const bf16_t* kvb = kvbf + (size_t)b * 8192;       // 8 heads * 1024 bf16
    const float*  ksb = kvbuf + (size_t)b * 8448;      // 8 heads * 1056 f32
#pragma unroll
    for (int h = 0; h < 8; ++h) {
        // denominator: q[m=l15][h*32 + quad*8+j] . ksum
        f32x4 ks0 = *(const f32x4*)&ksb[h * 1056 + 1024 + q8];
        f32x4 ks1 = *(const f32x4*)&ksb[h * 1056 + 1024 + q8 + 4];
        float den = 0.f;
#pragma unroll
        for (int j = 0; j < 4; ++j) den += (float)a[h][j] * ks0[j];
#pragma unroll
        for (int j = 0; j < 4; ++j) den += (float)a[h][4 + j] * ks1[j];
        den += __shfl_xor(den, 16);                    // reduce across quads
        den += __shfl_xor(den, 32);
        float z = 1.f / (den + 1e-6f);                 // z for row = l15
        float zr[4];
#pragma unroll
        for (int r = 0; r < 4; ++r) zr[r] = __shfl(z, quad * 4 + r, 16);
        // numerator: B[k=d][n=e] = kv[d][e], stored e-major -> contiguous frag
        bf16x8 b0 = *(const bf16x8*)&kvb[h * 1024 + l15 * 32 + q8];
        bf16x8 b1 = *(const bf16x8*)&kvb[h * 1024 + (16 + l15) * 32 + q8];
        f32x4 at0 = {}, at1 = {};
        at0 = __builtin_amdgcn_mfma_f32_16x16x32_bf16(a[h], b0, at0, 0, 0, 0);
        at1 = __builtin_amdgcn_mfma_f32_16x16x32_bf16(a[h], b1, at1, 0, 0, 0);
#pragma unroll
        for (int r = 0; r < 4; ++r) {                  // C-layout: row=quad*4+r, col=l15
            hs[(quad * 4 + r) * 264 + h * 32 + l15]      = (bf16_t)(at0[r] * zr[r]);
            hs[(quad * 4 + r) * 264 + h * 32 + 16 + l15] = (bf16_t)(at1[r] * zr[r]);
        }
    }
    // wave-local C->A layout round-trip (in-order DS pipe within wave)
    bf16x8 a2[8];
#pragma unroll
    for (int kk = 0; kk < 8; ++kk)
        a2[kk] = *(const bf16x8*)&hs[l15 * 264 + kk * 32 + q8];
    __syncthreads();       // sm0 chunk0 staged; all waves done with hs (sm1)
    // ---------------- Wo GEMM, 8 chunks of 32 cols, ping-pong sm0/sm1 --------
    f32x4 acc[16] = {};
    for (int nc = 0; nc < 8; ++nc) {
        if (nc < 7) stage_swz(Wo_t + (size_t)(nc + 1) * 32 * 256,
                              (nc & 1) ? sm0 : sm1, tid, 1024, 5, 256);
        const bf16_t* buf = (nc & 1) ? sm1 : sm0;
#pragma unroll
        for (int kk = 0; kk < 8; ++kk) {
#pragma unroll
            for (int s = 0; s < 2; ++s) {
                bf16x8 bb = rd_swz(buf, s * 16 + l15, kk * 4 + quad, 5);
                acc[nc * 2 + s] = __builtin_amdgcn_mfma_f32_16x16x32_bf16(a2[kk], bb, acc[nc * 2 + s], 0, 0, 0);
            }
        }
        __syncthreads();   // publishes next chunk, protects current from overwrite
    }
    // ---------------- epilogue: bias + x residual + LN1 ----------------
    float s1[4] = {}, s2[4] = {};
#pragma unroll
    for (int s = 0; s < 16; ++s) {
        int n = s * 16 + l15;
        float bias = (float)pbuf[768 + n];
#pragma unroll
        for (int r = 0; r < 4; ++r) {
            int m = m0 + wave * 16 + quad * 4 + r;
            float val = acc[s][r] + bias + ld_any(xraw, (size_t)m * 256 + n, f);
            acc[s][r] = val;
            s1[r] += val; s2[r] += val * val;
        }
    }
#pragma unroll
    for (int r = 0; r < 4; ++r) {
        float ts = quad_sum(s1[r]), ts2 = quad_sum(s2[r]);
        float mu = ts * (1.f / 256.f);
        float rs = rsqrtf(ts2 * (1.f / 256.f) - mu * mu + 1e-5f);
        s1[r] = mu; s2[r] = rs;
    }
#pragma unroll
    for (int s = 0; s < 16; ++s) {
        int n = s * 16 + l15;
        float gn = (float)pbuf[2304 + n], bn = (float)pbuf[2560 + n];
#pragma unroll
        for (int r = 0; r < 4; ++r) {
            int m = m0 + wave * 16 + quad * 4 + r;
            x1[(size_t)m * 256 + n] = (bf16_t)((acc[s][r] - s1[r]) * s2[r] * gn + bn);
        }
    }
}

// ------------------------------------------------- K5: fused FFN + LN2
// Round 6: M=128 per block (512 blocks). Round-5 PMC showed VALUBusy 38% >
// MfmaUtil 20% -- per-chunk overhead (staging index math, B-frag read
// addressing, hs round-trip) is row-count-invariant, so doubling rows/block
// halves overhead per row: each wave owns 2 m-subtiles (32 rows) and every
// staged chunk + every B-fragment read feeds 2x the MFMAs. Total weight
// re-stream halves (1GB -> 0.5GB); 512 blocks = exactly 2/CU, no tail.
// Keeps the proven machinery: stage_swz, conflict-free w2ff pack (r5),
// double-buffer + 1 barrier/chunk. Regs: acc 128 AGPR + a-frags 64 VGPR
// + temps ~= 240 <= 256 at 2 waves/SIMD. LDS 74KB x 2 = 148 <= 160.
__global__ __launch_bounds__(256, 2) void k_ff_ln2(
    const bf16_t* __restrict__ x1, const bf16_t* __restrict__ W1_t,
    const bf16_t* __restrict__ W2_t, const bf16_t* __restrict__ pbuf,
    const int* __restrict__ flag, void* __restrict__ out) {
    const int f32o = *flag;
    const int mt = blockIdx.x;                        // 512 blocks, 128 rows each
    const int tid = threadIdx.x, wave = tid >> 6, lane = tid & 63;
    const int l15 = lane & 15, quad = lane >> 4, q8 = quad * 8;
    __shared__ __align__(16) bf16_t w1s[2][8192];     // 32 ff-rows x 256 K each
    __shared__ __align__(16) bf16_t w2s[2][8192];     // [128][64] packed chunk
    __shared__ __align__(16) bf16_t hs[4][2][16][40]; // wave x m-subtile h buf
    const int m0 = mt * 128 + wave * 32;              // wave's first row
    bf16x8 a[2][8];
    ld_afrags(x1 + (size_t)m0 * 256, l15,      q8, a[0]);
    ld_afrags(x1 + (size_t)m0 * 256, 16 + l15, q8, a[1]);
    stage_swz(W1_t, w1s[0], tid, 1024, 5, 256);
    stage_w2ff(W2_t, 0, w2s[0], tid);
    __syncthreads();
    f32x4 acc[2][16] = {};
    for (int ch = 0; ch < 32; ++ch) {
        const int cur = ch & 1;
        // prefetch next chunk into the idle buffers (latency hides under MFMAs)
        if (ch < 31) {
            stage_swz(W1_t + (size_t)(ch + 1) * 32 * 256, w1s[cur ^ 1], tid, 1024, 5, 256);
            stage_w2ff(W2_t, ch + 1, w2s[cur ^ 1], tid);
        }
        // step a: h = relu(x1 @ W1_chunk + b1), 32 ff-cols, 2 m-subtiles
        f32x4 h0[2] = {}, h1[2] = {};
#pragma unroll
        for (int kk = 0; kk < 8; ++kk) {
#pragma unroll
            for (int s = 0; s < 2; ++s) {
                bf16x8 b = rd_swz(w1s[cur], s * 16 + l15, kk * 4 + quad, 5);
                h0[s] = __builtin_amdgcn_mfma_f32_16x16x32_bf16(a[0][kk], b, h0[s], 0, 0, 0);
                h1[s] = __builtin_amdgcn_mfma_f32_16x16x32_bf16(a[1][kk], b, h1[s], 0, 0, 0);
            }
        }
#pragma unroll
        for (int s = 0; s < 2; ++s) {
            float bias = (float)pbuf[1024 + ch * 32 + s * 16 + l15];
#pragma unroll
            for (int r = 0; r < 4; ++r) {
                float v0 = h0[s][r] + bias;
                float v1 = h1[s][r] + bias;
                hs[wave][0][quad * 4 + r][s * 16 + l15] = (bf16_t)(v0 > 0.f ? v0 : 0.f);
                hs[wave][1][quad * 4 + r][s * 16 + l15] = (bf16_t)(v1 > 0.f ? v1 : 0.f);
            }
        }
        // wave-local C->A layout round-trip (in-order DS pipe within wave)
        bf16x8 a2_0 = *(const bf16x8*)&hs[wave][0][l15][q8];
        bf16x8 a2_1 = *(const bf16x8*)&hs[wave][1][l15][q8];
        // step b: out += h_chunk @ W2_chunk (B-frag shared across m-subtiles)
#pragma unroll
        for (int s = 0; s < 16; ++s) {
            bf16x8 b0 = rd_w2ff(w2s[cur], s * 16 + l15, quad);
            acc[0][s] = __builtin_amdgcn_mfma_f32_16x16x32_bf16(a2_0, b0, acc[0][s], 0, 0, 0);
            acc[1][s] = __builtin_amdgcn_mfma_f32_16x16x32_bf16(a2_1, b0, acc[1][s], 0, 0, 0);
        }
        __syncthreads();   // next-chunk stages complete; cur buffers reusable
    }
    // epilogue: + b2 + x1 residual, LN2, dual-dtype store (per m-subtile)
#pragma unroll
    for (int mm = 0; mm < 2; ++mm) {
        float s1[4] = {}, s2[4] = {};
#pragma unroll
        for (int s = 0; s < 16; ++s) {
            int n = s * 16 + l15;
            float bias = (float)pbuf[2048 + n];
#pragma unroll
            for (int r = 0; r < 4; ++r) {
                int m = m0 + mm * 16 + quad * 4 + r;
                float val = acc[mm][s][r] + bias + (float)x1[(size_t)m * 256 + n];
                acc[mm][s][r] = val;
                s1[r] += val; s2[r] += val * val;
            }
        }
#pragma unroll
        for (int r = 0; r < 4; ++r) {
            float ts = quad_sum(s1[r]), ts2 = quad_sum(s2[r]);
            float mu = ts * (1.f / 256.f);
            float rs = rsqrtf(ts2 * (1.f / 256.f) - mu * mu + 1e-5f);
            s1[r] = mu; s2[r] = rs;
        }
#pragma unroll
        for (int s = 0; s < 16; ++s) {
            int n = s * 16 + l15;
            float gn = (float)pbuf[2816 + n], bn = (float)pbuf[3072 + n];
#pragma unroll
            for (int r = 0; r < 4; ++r) {
                int m = m0 + mm * 16 + quad * 4 + r;
                float val = (acc[mm][s][r] - s1[r]) * s2[r] * gn + bn;
                if (f32o) ((float*)out)[(size_t)m * 256 + n] = val;
                else      ((bf16_t*)out)[(size_t)m * 256 + n] = (bf16_t)val;
            }
        }
    }
}

// ------------------------------------------------- launch
extern "C" void kernel_launch(void* const* d_in, const int* in_sizes, int n_in,
                              void* d_out, int out_size, void* d_ws, size_t ws_size,
                              hipStream_t stream) {
    char* ws = (char*)d_ws;
    int*    flag   = (int*)ws;                              // 4 B (256 reserved)
    bf16_t* xbf    = (bf16_t*)(ws + 256);                   // 16.7M elems
    bf16_t* Wqkv_t = (bf16_t*)(ws + 33554688);              // 196608
    bf16_t* Wo_t   = (bf16_t*)(ws + 33947904);              // 65536
    bf16_t* W1_t   = (bf16_t*)(ws + 34078976);              // 262144
    bf16_t* W2_t   = (bf16_t*)(ws + 34603264);              // 262144
    bf16_t* pbuf   = (bf16_t*)(ws + 35127552);              // 3328
    float*  kvbuf  = (float*)(ws + 35134208);               // 33792 f32
    bf16_t* bufQ   = (bf16_t*)(ws + 35269376);              // 16.7M elems
    bf16_t* bufK   = bufQ + (size_t)NTOK * 256;
    bf16_t* bufV   = bufK + (size_t)NTOK * 256;
    bf16_t* kvbf   = bufV;    // V dead after k_kvsum; reuse 64KB for bf16 kv
    bf16_t* bufX1  = bufQ;    // Q read + overwritten row-local in k_attn_wo_ln1

    k_detect<<<1, 256, 0, stream>>>(d_in[0], flag);
    k_convert<<<16384, 256, 0, stream>>>(d_in[0], flag, xbf);
    k_prep<<<3217, 256, 0, stream>>>(d_in[1], d_in[3], d_in[5], d_in[7],
                                     d_in[9], d_in[11],
                                     d_in[2], d_in[4], d_in[6], d_in[8],
                                     d_in[10], d_in[12],
                                     d_in[13], d_in[14], d_in[15], d_in[16],
                                     flag, Wqkv_t, Wo_t, W1_t, W2_t, pbuf, kvbuf);
    k_qkv<<<dim3(1024, 6), 256, 0, stream>>>(xbf, Wqkv_t, pbuf, bufQ, bufK, bufV);
    k_kvsum<<<2048, 256, 0, stream>>>(bufK, bufV, kvbuf);
    k_kvprep<<<32, 256, 0, stream>>>(kvbuf, kvbf);
    k_attn_wo_ln1<<<1024, 256, 0, stream>>>(bufQ, kvbf, kvbuf, Wo_t, pbuf,
                                            d_in[0], flag, bufX1);
    k_ff_ln2<<<512, 256, 0, stream>>>(bufX1, W1_t, W2_t, pbuf, flag, d_out);
}

// Round 7
// 404.764 us; speedup vs baseline: 1.0681x; 1.0105x over previous
//
#include <hip/hip_runtime.h>
#include <hip/hip_bf16.h>
#include <math.h>

#define NTOK   65536
#define L_SEQ  16384

typedef __bf16 bf16_t;
typedef bf16_t bf16x8 __attribute__((ext_vector_type(8)));
typedef bf16_t bf16x4 __attribute__((ext_vector_type(4)));
typedef float  f32x4  __attribute__((ext_vector_type(4)));

__device__ inline float phi_f(float x) { return x > 0.f ? x + 1.f : __expf(x); }

__device__ inline float quad_sum(float v) {
    v += __shfl_xor(v, 1);
    v += __shfl_xor(v, 2);
    v += __shfl_xor(v, 4);
    v += __shfl_xor(v, 8);
    return v;
}

__device__ inline float ld_any(const void* p, size_t i, int f32) {
    return f32 ? ((const float*)p)[i] : (float)((const bf16_t*)p)[i];
}

// async 16B global->LDS (direct-to-shared DMA; HW dest = wave-uniform base +
// lane*16 — callers below always pass lds ptrs of exactly that shape)
__device__ inline void async_copy16(const bf16_t* g, bf16_t* l) {
    __builtin_amdgcn_global_load_lds(
        (const __attribute__((address_space(1))) unsigned int*)g,
        (__attribute__((address_space(3))) unsigned int*)l, 16, 0, 0);
}

// Stage nslot 16-B units (8 bf16 each; nslot = elements/8) of a
// [rows][rowstride] bf16 slice into LDS with an XOR swizzle of the
// (1<<ulog2) units per row: phys j = u ^ (n & (U-1)).
__device__ inline void stage_swz(const bf16_t* __restrict__ g, bf16_t* lds,
                                 int tid, int nslot, int ulog2, int rowstride) {
    const int umask = (1 << ulog2) - 1;
    for (int s = tid; s < nslot; s += 256) {
        int n = s >> ulog2, j = s & umask;
        int u = j ^ (n & umask);
        async_copy16(g + (size_t)n * rowstride + u * 8, lds + (size_t)s * 8);
    }
}

__device__ inline bf16x8 rd_swz(const bf16_t* lds, int n, int u, int ulog2) {
    int j = u ^ (n & ((1 << ulog2) - 1));
    return *(const bf16x8*)&lds[(((size_t)n << ulog2) + j) * 8];
}

// ---- W2 chunk [256 n][32 k] packed as [128 rows][64 cols] so LDS rows span
// 128B = all 32 banks. Row r = n&127, slot u = (n>>7)*4 + k/8, phys = u^(r&7).
// Verified conflict-free in round 5.
__device__ inline void stage_w2ff(const bf16_t* __restrict__ W2_t, int ch,
                                  bf16_t* lds, int tid) {
    for (int S = tid; S < 1024; S += 256) {
        int r = S >> 3, phys = S & 7;
        int u = phys ^ (r & 7);
        int n = ((u >> 2) << 7) + r;
        int ks = u & 3;
        async_copy16(W2_t + (size_t)n * 1024 + ch * 32 + ks * 8, lds + (size_t)S * 8);
    }
}

__device__ inline bf16x8 rd_w2ff(const bf16_t* lds, int n, int quad) {
    int r = n & 127;
    int u = ((n >> 7) << 2) + quad;
    int phys = u ^ (r & 7);
    return *(const bf16x8*)&lds[(size_t)(r * 8 + phys) * 8];
}

// A-frags for one wave: row m, k = kk*32 + quad*8, kk=0..7 (K=256)
__device__ inline void ld_afrags(const bf16_t* __restrict__ tile, int row, int q8,
                                 bf16x8 a[8]) {
#pragma unroll
    for (int kk = 0; kk < 8; ++kk)
        a[kk] = *(const bf16x8*)&tile[(size_t)row * 256 + kk * 32 + q8];
}

// ------------------------------------------------- K-1: dtype probe
__global__ __launch_bounds__(256) void k_detect(const void* __restrict__ xraw,
                                                int* __restrict__ flag) {
    __shared__ int bad;
    if (threadIdx.x == 0) bad = 0;
    __syncthreads();
    const bf16_t* xb = (const bf16_t*)xraw;
    int mybad = 0;
#pragma unroll
    for (int j = 0; j < 16; ++j) {
        float v = fabsf((float)xb[threadIdx.x + 256 * j]);
        if (!(v <= 1000.f)) mybad = 1;
    }
    if (mybad) atomicOr(&bad, 1);
    __syncthreads();
    if (threadIdx.x == 0) *flag = bad;
}

// ------------------------------------------------- K0a: x -> canonical bf16
__global__ __launch_bounds__(256) void k_convert(const void* __restrict__ xraw,
                                                 const int* __restrict__ flag,
                                                 bf16_t* __restrict__ xbf) {
    const int f = *flag;
    size_t i = ((size_t)blockIdx.x * 256 + threadIdx.x) * 4;
    if (f) {
        f32x4 v = *(const f32x4*)((const float*)xraw + i);
        bf16x4 o;
#pragma unroll
        for (int j = 0; j < 4; ++j) o[j] = (bf16_t)v[j];
        *(bf16x4*)&xbf[i] = o;
    } else {
        *(bf16x4*)&xbf[i] = *(const bf16x4*)((const bf16_t*)xraw + i);
    }
}

// ------------------------------------------------- K0b: weight transpose + bias pack
__global__ __launch_bounds__(256) void k_prep(
    const void* __restrict__ Wq, const void* __restrict__ Wk,
    const void* __restrict__ Wv, const void* __restrict__ Wo,
    const void* __restrict__ W1, const void* __restrict__ W2,
    const void* __restrict__ bq, const void* __restrict__ bk,
    const void* __restrict__ bv, const void* __restrict__ bo,
    const void* __restrict__ b1, const void* __restrict__ b2,
    const void* __restrict__ g1, const void* __restrict__ be1,
    const void* __restrict__ g2, const void* __restrict__ be2,
    const int* __restrict__ flag,
    bf16_t* __restrict__ Wqkv_t, bf16_t* __restrict__ Wo_t,
    bf16_t* __restrict__ W1_t, bf16_t* __restrict__ W2_t,
    bf16_t* __restrict__ pbuf, float* __restrict__ kvbuf) {
    const int f = *flag;
    int idx = blockIdx.x * 256 + threadIdx.x;
    if (idx < 196608) {                       // Wqkv_t [768][256]
        int n = idx >> 8, k = idx & 255;
        float v;
        if (n < 256)      v = ld_any(Wq, k * 256 + n, f);
        else if (n < 512) v = ld_any(Wk, k * 256 + (n - 256), f);
        else              v = ld_any(Wv, k * 256 + (n - 512), f);
        Wqkv_t[idx] = (bf16_t)v;
    } else if (idx < 262144) {                // Wo_t [256][256]
        int i = idx - 196608; int n = i >> 8, k = i & 255;
        Wo_t[i] = (bf16_t)ld_any(Wo, k * 256 + n, f);
    } else if (idx < 524288) {                // W1_t [1024][256]
        int i = idx - 262144; int n = i >> 8, k = i & 255;
        W1_t[i] = (bf16_t)ld_any(W1, k * 1024 + n, f);
    } else if (idx < 786432) {                // W2_t [256][1024]
        int i = idx - 524288; int n = i >> 10, k = i & 1023;
        W2_t[i] = (bf16_t)ld_any(W2, k * 256 + n, f);
    } else if (idx < 820224) {                // KV state zero-init
        kvbuf[idx - 786432] = 0.f;
    } else if (idx < 823552) {                // bias/param pack
        int i = idx - 820224;
        float v;
        if (i < 256)        v = ld_any(bq, i, f);
        else if (i < 512)   v = ld_any(bk, i - 256, f);
        else if (i < 768)   v = ld_any(bv, i - 512, f);
        else if (i < 1024)  v = ld_any(bo, i - 768, f);
        else if (i < 2048)  v = ld_any(b1, i - 1024, f);
        else if (i < 2304)  v = ld_any(b2, i - 2048, f);
        else if (i < 2560)  v = ld_any(g1, i - 2304, f);
        else if (i < 2816)  v = ld_any(be1, i - 2560, f);
        else if (i < 3072)  v = ld_any(g2, i - 2816, f);
        else                v = ld_any(be2, i - 3072, f);
        pbuf[i] = (bf16_t)v;
    }
}

// ------------------------------------------------- K1: QKV GEMM + phi
// Round 7: M=128 per block (grid 512x6), round-6 lever applied: 2 m-subtiles
// per wave share every staged chunk + every B-fragment read -> 128 MFMAs/wave
// per tile vs 64, weight L2 restream halves (402->201MB). Regs: a 64 VGPR +
// acc 64 AGPR (~170 total) -> launch_bounds(256,3); LDS 64KB -> 2 blocks/CU.
__global__ __launch_bounds__(256, 3) void k_qkv(
    const bf16_t* __restrict__ x, const bf16_t* __restrict__ Wqkv_t,
    const bf16_t* __restrict__ pbuf,
    bf16_t* __restrict__ q_phi, bf16_t* __restrict__ k_phi,
    bf16_t* __restrict__ v_out) {
    const int mt = blockIdx.x, nt = blockIdx.y;
    const int tid = threadIdx.x, wave = tid >> 6, lane = tid & 63;
    const int l15 = lane & 15, quad = lane >> 4, q8 = quad * 8;
    __shared__ __align__(16) bf16_t bs[128 * 256];
    const int m0 = mt * 128;
    bf16x8 a[2][8];
    ld_afrags(x + (size_t)m0 * 256,        wave * 16 + l15, q8, a[0]);
    ld_afrags(x + (size_t)(m0 + 64) * 256, wave * 16 + l15, q8, a[1]);
    stage_swz(Wqkv_t + (size_t)nt * 128 * 256, bs, tid, 4096, 5, 256);
    __syncthreads();
    f32x4 acc[2][8] = {};
#pragma unroll
    for (int kk = 0; kk < 8; ++kk) {
#pragma unroll
        for (int s = 0; s < 8; ++s) {
            bf16x8 b = rd_swz(bs, s * 16 + l15, kk * 4 + quad, 5);
            acc[0][s] = __builtin_amdgcn_mfma_f32_16x16x32_bf16(a[0][kk], b, acc[0][s], 0, 0, 0);
            acc[1][s] = __builtin_amdgcn_mfma_f32_16x16x32_bf16(a[1][kk], b, acc[1][s], 0, 0, 0);
        }
    }
#pragma unroll
    for (int s = 0; s < 8; ++s) {
        int ng = nt * 128 + s * 16 + l15;
        bf16_t* dst = ng < 256 ? q_phi : (ng < 512 ? k_phi : v_out);
        int nl = ng & 255;
        float bias = (float)pbuf[(ng < 256 ? 0 : (ng < 512 ? 256 : 512)) + nl];
#pragma unroll
        for (int mm = 0; mm < 2; ++mm) {
#pragma unroll
            for (int r = 0; r < 4; ++r) {
                int m = m0 + mm * 64 + wave * 16 + quad * 4 + r;
                float val = acc[mm][s][r] + bias;
                if (ng < 512) val = phi_f(val);
                dst[(size_t)m * 256 + nl] = (bf16_t)val;
            }
        }
    }
}

// ------------------------------------------------- K2: KV state reduction
// Writes kv TRANSPOSED: kvbuf slot [e*32+d] = sum_l k_phi[l][d]*v[l][e]
// (e-major so the apply-side MFMA B-fragment is one contiguous bf16x8).
__global__ __launch_bounds__(256) void k_kvsum(
    const bf16_t* __restrict__ k_phi, const bf16_t* __restrict__ v_in,
    float* __restrict__ kvbuf) {
    const int bid = blockIdx.x;
    const int bh = bid >> 6, ck = bid & 63;
    const int b = bh >> 3, h = bh & 7;
    const int tid = threadIdx.x;
    __shared__ float ks[32][33], vs[32][33];
    const size_t base = ((size_t)b * L_SEQ + ck * 256) * 256 + h * 32;
    const int row = tid >> 3, c4 = (tid & 7) * 4;
    const int d = row, e4 = c4;
    float acc[4] = {}, ksacc = 0.f;
    for (int it = 0; it < 8; ++it) {
        bf16x4 kk4 = *(const bf16x4*)&k_phi[base + (size_t)(it * 32 + row) * 256 + c4];
        bf16x4 vv4 = *(const bf16x4*)&v_in[base + (size_t)(it * 32 + row) * 256 + c4];
#pragma unroll
        for (int j = 0; j < 4; ++j) { ks[row][c4 + j] = (float)kk4[j]; vs[row][c4 + j] = (float)vv4[j]; }
        __syncthreads();
#pragma unroll
        for (int ii = 0; ii < 32; ++ii) {
            float kd = ks[ii][d];
            ksacc += kd;
#pragma unroll
            for (int j = 0; j < 4; ++j) acc[j] += kd * vs[ii][e4 + j];
        }
        __syncthreads();
    }
    float* kvdst = kvbuf + (size_t)bh * 1056;
#pragma unroll
    for (int j = 0; j < 4; ++j) atomicAdd(&kvdst[(e4 + j) * 32 + d], acc[j]);
    if ((tid & 7) == 0) atomicAdd(&kvdst[1024 + d], ksacc);
}

// ------------------------------------------------- K2b: kv f32 -> bf16 pack
// kvbf[bh*1024 + e*32 + d] = (bf16) kvbuf[bh*1056 + e*32 + d]
__global__ __launch_bounds__(256) void k_kvprep(const float* __restrict__ kvbuf,
                                                bf16_t* __restrict__ kvbf) {
    int idx = blockIdx.x * 256 + threadIdx.x;       // 8192 total
    int bh = idx >> 8, r4 = (idx & 255) * 4;
    f32x4 v = *(const f32x4*)&kvbuf[(size_t)bh * 1056 + r4];
    bf16x4 o;
#pragma unroll
    for (int j = 0; j < 4; ++j) o[j] = (bf16_t)v[j];
    *(bf16x4*)&kvbf[(size_t)bh * 1024 + r4] = o;
}

// ------------------------------------------------- K3+K4 fused: attention
// apply (q_phi @ kv * z) + @Wo + x residual + LN1.
// Round 7: M=128 per block (512 blocks). Attention phase runs per m-subtile
// sequentially, reusing the same wave-private hs (in-order DS pipe, no
// barrier); Wo GEMM shares each staged B-fragment across 2 m-subtiles.
// Wo restream halves (128->64MB). Regs: a2 64 VGPR + acc 128 AGPR ~= 256
// total -> launch_bounds(256,2) (= the budget k_ff_ln2 proved at 2 blk/CU).
// LDS unchanged: sm0 16KB + sm1 33KB = 49.4KB.
__global__ __launch_bounds__(256, 2) void k_attn_wo_ln1(
    const bf16_t* __restrict__ q_phi, const bf16_t* __restrict__ kvbf,
    const float* __restrict__ kvbuf, const bf16_t* __restrict__ Wo_t,
    const bf16_t* __restrict__ pbuf, const void* __restrict__ xraw,
    const int* __restrict__ flag, bf16_t* __restrict__ x1) {
    const int f = *flag;
    const int mt = blockIdx.x;
    const int tid = threadIdx.x, wave = tid >> 6, lane = tid & 63;
    const int l15 = lane & 15, quad = lane >> 4, q8 = quad * 8;
    __shared__ __align__(16) bf16_t sm0[8192];         // Wo chunk (nc even), 16KB
    __shared__ __align__(16) bf16_t sm1[16896];        // hs, then Wo chunk (nc odd)
    const int m0 = mt * 128;
    const int b = m0 >> 14;                            // batch (128-row blocks never straddle)
    stage_swz(Wo_t, sm0, tid, 1024, 5, 256);           // async chunk0 (32 rows)
    // ---------------- attention phase (wave-local, no barrier) ----------------
    bf16_t* hs = sm1 + wave * (16 * 264);              // [16 rows][264 cols]
    const bf16_t* kvb = kvbf + (size_t)b * 8192;       // 8 heads * 1024 bf16
    const float*  ksb = kvbuf + (size_t)b * 8448;      // 8 heads * 1056 f32
    bf16x8 a2[2][8];
#pragma unroll
    for (int mm = 0; mm < 2; ++mm) {
        bf16x8 a[8];
        ld_afrags(q_phi + (size_t)(m0 + mm * 64) * 256, wave * 16 + l15, q8, a);
#pragma unroll
        for (int h = 0; h < 8; ++h) {
            // denominator: q[m=l15][h*32 + quad*8+j] . ksum
            f32x4 ks0 = *(const f32x4*)&ksb[h * 1056 + 1024 + q8];
            f32x4 ks1 = *(const f32x4*)&ksb[h * 1056 + 1024 + q8 + 4];
            float den = 0.f;
#pragma unroll
            for (int j = 0; j < 4; ++j) den += (float)a[h][j] * ks0[j];
#pragma unroll
            for (int j = 0; j < 4; ++j) den += (float)a[h][4 + j] * ks1[j];
            den += __shfl_xor(den, 16);                // reduce across quads
            den += __shfl_xor(den, 32);
            float z = 1.f / (den + 1e-6f);             // z for row = l15
            float zr[4];
#pragma unroll
            for (int r = 0; r < 4; ++r) zr[r] = __shfl(z, quad * 4 + r, 16);
            // numerator: B[k=d][n=e] = kv[d][e], e-major -> contiguous frag
            bf16x8 b0 = *(const bf16x8*)&kvb[h * 1024 + l15 * 32 + q8];
            bf16x8 b1 = *(const bf16x8*)&kvb[h * 1024 + (16 + l15) * 32 + q8];
            f32x4 at0 = {}, at1 = {};
            at0 = __builtin_amdgcn_mfma_f32_16x16x32_bf16(a[h], b0, at0, 0, 0, 0);
            at1 = __builtin_amdgcn_mfma_f32_16x16x32_bf16(a[h], b1, at1, 0, 0, 0);
#pragma unroll
            for (int r = 0; r < 4; ++r) {              // C-layout: row=quad*4+r, col=l15
                hs[(quad * 4 + r) * 264 + h * 32 + l15]      = (bf16_t)(at0[r] * zr[r]);
                hs[(quad * 4 + r) * 264 + h * 32 + 16 + l15] = (bf16_t)(at1[r] * zr[r]);
            }
        }
        // wave-local C->A layout round-trip (in-order DS pipe within wave)
#pragma unroll
        for (int kk = 0; kk < 8; ++kk)
            a2[mm][kk] = *(const bf16x8*)&hs[l15 * 264 + kk * 32 + q8];
    }
    __syncthreads();       // sm0 chunk0 staged; all waves done with hs (sm1)
    // ---------------- Wo GEMM, 8 chunks of 32 cols, ping-pong sm0/sm1 --------
    f32x4 acc[2][16] = {};
    for (int nc = 0; nc < 8; ++nc) {
        if (nc < 7) stage_swz(Wo_t + (size_t)(nc + 1) * 32 * 256,
                              (nc & 1) ? sm0 : sm1, tid, 1024, 5, 256);
        const bf16_t* buf = (nc & 1) ? sm1 : sm0;
#pragma unroll
        for (int kk = 0; kk < 8; ++kk) {
#pragma unroll
            for (int s = 0; s < 2; ++s) {
                bf16x8 bb = rd_swz(buf, s * 16 + l15, kk * 4 + quad, 5);
                acc[0][nc * 2 + s] = __builtin_amdgcn_mfma_f32_16x16x32_bf16(a2[0][kk], bb, acc[0][nc * 2 + s], 0, 0, 0);
                acc[1][nc * 2 + s] = __builtin_amdgcn_mfma_f32_16x16x32_bf16(a2[1][kk], bb, acc[1][nc * 2 + s], 0, 0, 0);
            }
        }
        __syncthreads();   // publishes next chunk, protects current from overwrite
    }
    // ---------------- epilogue: bias + x residual + LN1 (per m-subtile) ------
#pragma unroll
    for (int mm = 0; mm < 2; ++mm) {
        float s1[4] = {}, s2[4] = {};
#pragma unroll
        for (int s = 0; s < 16; ++s) {
            int n = s * 16 + l15;
            float bias = (float)pbuf[768 + n];
#pragma unroll
            for (int r = 0; r < 4; ++r) {
                int m = m0 + mm * 64 + wave * 16 + quad * 4 + r;
                float val = acc[mm][s][r] + bias + ld_any(xraw, (size_t)m * 256 + n, f);
                acc[mm][s][r] = val;
                s1[r] += val; s2[r] += val * val;
            }
        }
#pragma unroll
        for (int r = 0; r < 4; ++r) {
            float ts = quad_sum(s1[r]), ts2 = quad_sum(s2[r]);
            float mu = ts * (1.f / 256.f);
            float rs = rsqrtf(ts2 * (1.f / 256.f) - mu * mu + 1e-5f);
            s1[r] = mu; s2[r] = rs;
        }
#pragma unroll
        for (int s = 0; s < 16; ++s) {
            int n = s * 16 + l15;
            float gn = (float)pbuf[2304 + n], bn = (float)pbuf[2560 + n];
#pragma unroll
            for (int r = 0; r < 4; ++r) {
                int m = m0 + mm * 64 + wave * 16 + quad * 4 + r;
                x1[(size_t)m * 256 + n] = (bf16_t)((acc[mm][s][r] - s1[r]) * s2[r] * gn + bn);
            }
        }
    }
}

// ------------------------------------------------- K5: fused FFN + LN2
// M=128 per block (512 blocks), double-buffer + 1 barrier/chunk, conflict-free
// w2ff pack. (Round-6 verified: 117us, MfmaUtil 24%.) Unchanged this round.
__global__ __launch_bounds__(256, 2) void k_ff_ln2(
    const bf16_t* __restrict__ x1, const bf16_t* __restrict__ W1_t,
    const bf16_t* __restrict__ W2_t, const bf16_t* __restrict__ pbuf,
    const int* __restrict__ flag, void* __restrict__ out) {
    const int f32o = *flag;
    const int mt = blockIdx.x;                        // 512 blocks, 128 rows each
    const int tid = threadIdx.x, wave = tid >> 6, lane = tid & 63;
    const int l15 = lane & 15, quad = lane >> 4, q8 = quad * 8;
    __shared__ __align__(16) bf16_t w1s[2][8192];     // 32 ff-rows x 256 K each
    __shared__ __align__(16) bf16_t w2s[2][8192];     // [128][64] packed chunk
    __shared__ __align__(16) bf16_t hs[4][2][16][40]; // wave x m-subtile h buf
    const int m0 = mt * 128 + wave * 32;              // wave's first row
    bf16x8 a[2][8];
    ld_afrags(x1 + (size_t)m0 * 256, l15,      q8, a[0]);
    ld_afrags(x1 + (size_t)m0 * 256, 16 + l15, q8, a[1]);
    stage_swz(W1_t, w1s[0], tid, 1024, 5, 256);
    stage_w2ff(W2_t, 0, w2s[0], tid);
    __syncthreads();
    f32x4 acc[2][16] = {};
    for (int ch = 0; ch < 32; ++ch) {
        const int cur = ch & 1;
        // prefetch next chunk into the idle buffers (latency hides under MFMAs)
        if (ch < 31) {
            stage_swz(W1_t + (size_t)(ch + 1) * 32 * 256, w1s[cur ^ 1], tid, 1024, 5, 256);
            stage_w2ff(W2_t, ch + 1, w2s[cur ^ 1], tid);
        }
        // step a: h = relu(x1 @ W1_chunk + b1), 32 ff-cols, 2 m-subtiles
        f32x4 h0[2] = {}, h1[2] = {};
#pragma unroll
        for (int kk = 0; kk < 8; ++kk) {
#pragma unroll
            for (int s = 0; s < 2; ++s) {
                bf16x8 b = rd_swz(w1s[cur], s * 16 + l15, kk * 4 + quad, 5);
                h0[s] = __builtin_amdgcn_mfma_f32_16x16x32_bf16(a[0][kk], b, h0[s], 0, 0, 0);
                h1[s] = __builtin_amdgcn_mfma_f32_16x16x32_bf16(a[1][kk], b, h1[s], 0, 0, 0);
            }
        }
#pragma unroll
        for (int s = 0; s < 2; ++s) {
            float bias = (float)pbuf[1024 + ch * 32 + s * 16 + l15];
#pragma unroll
            for (int r = 0; r < 4; ++r) {
                float v0 = h0[s][r] + bias;
                float v1 = h1[s][r] + bias;
                hs[wave][0][quad * 4 + r][s * 16 + l15] = (bf16_t)(v0 > 0.f ? v0 : 0.f);
                hs[wave][1][quad * 4 + r][s * 16 + l15] = (bf16_t)(v1 > 0.f ? v1 : 0.f);
            }
        }
        // wave-local C->A layout round-trip (in-order DS pipe within wave)
        bf16x8 a2_0 = *(const bf16x8*)&hs[wave][0][l15][q8];
        bf16x8 a2_1 = *(const bf16x8*)&hs[wave][1][l15][q8];
        // step b: out += h_chunk @ W2_chunk (B-frag shared across m-subtiles)
#pragma unroll
        for (int s = 0; s < 16; ++s) {
            bf16x8 b0 = rd_w2ff(w2s[cur], s * 16 + l15, quad);
            acc[0][s] = __builtin_amdgcn_mfma_f32_16x16x32_bf16(a2_0, b0, acc[0][s], 0, 0, 0);
            acc[1][s] = __builtin_amdgcn_mfma_f32_16x16x32_bf16(a2_1, b0, acc[1][s], 0, 0, 0);
        }
        __syncthreads();   // next-chunk stages complete; cur buffers reusable
    }
    // epilogue: + b2 + x1 residual, LN2, dual-dtype store (per m-subtile)
#pragma unroll
    for (int mm = 0; mm < 2; ++mm) {
        float s1[4] = {}, s2[4] = {};
#pragma unroll
        for (int s = 0; s < 16; ++s) {
            int n = s * 16 + l15;
            float bias = (float)pbuf[2048 + n];
#pragma unroll
            for (int r = 0; r < 4; ++r) {
                int m = m0 + mm * 16 + quad * 4 + r;
                float val = acc[mm][s][r] + bias + (float)x1[(size_t)m * 256 + n];
                acc[mm][s][r] = val;
                s1[r] += val; s2[r] += val * val;
            }
        }
#pragma unroll
        for (int r = 0; r < 4; ++r) {
            float ts = quad_sum(s1[r]), ts2 = quad_sum(s2[r]);
            float mu = ts * (1.f / 256.f);
            float rs = rsqrtf(ts2 * (1.f / 256.f) - mu * mu + 1e-5f);
            s1[r] = mu; s2[r] = rs;
        }
#pragma unroll
        for (int s = 0; s < 16; ++s) {
            int n = s * 16 + l15;
            float gn = (float)pbuf[2816 + n], bn = (float)pbuf[3072 + n];
#pragma unroll
            for (int r = 0; r < 4; ++r) {
                int m = m0 + mm * 16 + quad * 4 + r;
                float val = (acc[mm][s][r] - s1[r]) * s2[r] * gn + bn;
                if (f32o) ((float*)out)[(size_t)m * 256 + n] = val;
                else      ((bf16_t*)out)[(size_t)m * 256 + n] = (bf16_t)val;
            }
        }
    }
}

// ------------------------------------------------- launch
extern "C" void kernel_launch(void* const* d_in, const int* in_sizes, int n_in,
                              void* d_out, int out_size, void* d_ws, size_t ws_size,
                              hipStream_t stream) {
    char* ws = (char*)d_ws;
    int*    flag   = (int*)ws;                              // 4 B (256 reserved)
    bf16_t* xbf    = (bf16_t*)(ws + 256);                   // 16.7M elems
    bf16_t* Wqkv_t = (bf16_t*)(ws + 33554688);              // 196608
    bf16_t* Wo_t   = (bf16_t*)(ws + 33947904);              // 65536
    bf16_t* W1_t   = (bf16_t*)(ws + 34078976);              // 262144
    bf16_t* W2_t   = (bf16_t*)(ws + 34603264);              // 262144
    bf16_t* pbuf   = (bf16_t*)(ws + 35127552);              // 3328
    float*  kvbuf  = (float*)(ws + 35134208);               // 33792 f32
    bf16_t* bufQ   = (bf16_t*)(ws + 35269376);              // 16.7M elems
    bf16_t* bufK   = bufQ + (size_t)NTOK * 256;
    bf16_t* bufV   = bufK + (size_t)NTOK * 256;
    bf16_t* kvbf   = bufV;    // V dead after k_kvsum; reuse 64KB for bf16 kv
    bf16_t* bufX1  = bufQ;    // Q read + overwritten row-local in k_attn_wo_ln1

    k_detect<<<1, 256, 0, stream>>>(d_in[0], flag);
    k_convert<<<16384, 256, 0, stream>>>(d_in[0], flag, xbf);
    k_prep<<<3217, 256, 0, stream>>>(d_in[1], d_in[3], d_in[5], d_in[7],
                                     d_in[9], d_in[11],
                                     d_in[2], d_in[4], d_in[6], d_in[8],
                                     d_in[10], d_in[12],
                                     d_in[13], d_in[14], d_in[15], d_in[16],
                                     flag, Wqkv_t, Wo_t, W1_t, W2_t, pbuf, kvbuf);
    k_qkv<<<dim3(512, 6), 256, 0, stream>>>(xbf, Wqkv_t, pbuf, bufQ, bufK, bufV);
    k_kvsum<<<2048, 256, 0, stream>>>(bufK, bufV, kvbuf);
    k_kvprep<<<32, 256, 0, stream>>>(kvbuf, kvbf);
    k_attn_wo_ln1<<<512, 256, 0, stream>>>(bufQ, kvbf, kvbuf, Wo_t, pbuf,
                                           d_in[0], flag, bufX1);
    k_ff_ln2<<<512, 256, 0, stream>>>(bufX1, W1_t, W2_t, pbuf, flag, d_out);
}